// Round 1
// baseline (397.446 us; speedup 1.0000x reference)
//
#include <hip/hip_runtime.h>

// CausalSelfAttention: B=8, S=2048, D=512, fp32 in/out, Q=K=V=x, no scale.
// Strategy: convert x to bf16 (plus a transposed copy) in d_ws, then a
// flash-style online-softmax kernel using mfma_f32_16x16x32_bf16.
// ws layout: [0, 16 MiB) = x_bf16 [B][S][D]; [16 MiB, 32 MiB) = xT_bf16 [B][D][S].

#define S_LEN 2048
#define D_DIM 512

typedef short bf16x8 __attribute__((ext_vector_type(8)));
typedef float f32x4 __attribute__((ext_vector_type(4)));

__device__ __forceinline__ unsigned short f2b(float f) {
  unsigned int u = __float_as_uint(f);
  unsigned int r = (u + 0x7FFFu + ((u >> 16) & 1u)) >> 16;  // RNE
  return (unsigned short)r;
}

// ---------------------------------------------------------------------------
// Pre-pass: fp32 -> bf16, writing both row-major x_bf and transposed xT.
// Grid: 8 batches * 32 s-tiles * 8 d-tiles = 2048 blocks, 256 threads.
// 64x64 tile through LDS so both global writes are coalesced.
// ---------------------------------------------------------------------------
__global__ void convert_transpose_kernel(const float* __restrict__ x,
                                         unsigned short* __restrict__ xb,
                                         unsigned short* __restrict__ xT) {
  __shared__ unsigned short lds[64 * 72];  // [d_local][s_local], pad 72 vs 64
  const int bid = blockIdx.x;
  const int b   = bid >> 8;
  const int rem = bid & 255;
  const int s0  = (rem >> 3) * 64;
  const int d0  = (rem & 7) * 64;
  const int tid = threadIdx.x;
  #pragma unroll
  for (int it = 0; it < 4; ++it) {
    int idx = it * 256 + tid;        // 0..1023
    int row = idx >> 4;              // s_local 0..63
    int c4  = (idx & 15) * 4;        // d_local 0..60
    const float4 v = *(const float4*)(x + ((size_t)(b * S_LEN + s0 + row)) * D_DIM + d0 + c4);
    unsigned short h0 = f2b(v.x), h1 = f2b(v.y), h2 = f2b(v.z), h3 = f2b(v.w);
    ushort4 o; o.x = h0; o.y = h1; o.z = h2; o.w = h3;
    *(ushort4*)(xb + ((size_t)(b * S_LEN + s0 + row)) * D_DIM + d0 + c4) = o;
    lds[(c4 + 0) * 72 + row] = h0;
    lds[(c4 + 1) * 72 + row] = h1;
    lds[(c4 + 2) * 72 + row] = h2;
    lds[(c4 + 3) * 72 + row] = h3;
  }
  __syncthreads();
  #pragma unroll
  for (int it = 0; it < 4; ++it) {
    int idx  = it * 256 + tid;
    int drow = idx >> 4;             // d_local 0..63
    int s4   = (idx & 15) * 4;       // s_local 0..60
    ushort4 o = *(ushort4*)(&lds[drow * 72 + s4]);
    *(ushort4*)(xT + ((size_t)(b * D_DIM + d0 + drow)) * S_LEN + s0 + s4) = o;
  }
}

// ---------------------------------------------------------------------------
// Flash-style causal attention.
// Block = 256 threads = 4 waves; Q-tile = 32 rows; K-tile = 32 keys/iter.
// Wave roles: r = w>>1 picks 16 Q-rows (QK^T), c = w&1 picks 16 keys (QK^T);
//             each wave owns O[32 rows][128 d-cols] slice w for PV.
// MFMA 16x16x32 bf16 layouts (per guide, HW-verified):
//   A[m = lane&15][k = (lane>>4)*8 + j]   (8 bf16 / 4 VGPR)
//   B[k = (lane>>4)*8 + j][n = lane&15]
//   C/D: col = lane&15, row = (lane>>4)*4 + reg
// Grid: 512 blocks = 64 q-tiles * 8 batches. batch = bid&7 (XCD-pinned),
// qtile = 63 - (bid>>3): heaviest causal tiles dispatch first (load balance).
// ---------------------------------------------------------------------------
__global__ __launch_bounds__(256, 2)
void attn_kernel(const unsigned short* __restrict__ xb,
                 const unsigned short* __restrict__ xT,
                 float* __restrict__ out) {
  __shared__ float pmax[2][32];
  __shared__ float psum[2][32];
  __shared__ float mbuf[32];
  __shared__ float lbuf[32];
  __shared__ unsigned short Plds[32 * 40];  // [row][key], pad 40 vs 32

  const int bid   = blockIdx.x;
  const int batch = bid & 7;
  const int qtile = 63 - (bid >> 3);
  const int q0    = qtile * 32;
  const int tid   = threadIdx.x;
  const int w     = tid >> 6;
  const int lane  = tid & 63;
  const int r     = w >> 1, c = w & 1;
  const int l15   = lane & 15, quad = lane >> 4;

  if (tid < 32) { mbuf[tid] = -1e38f; lbuf[tid] = 0.0f; }
  __syncthreads();

  // Q fragments in registers: wave's 16 rows x full D=512.
  bf16x8 qf[16];
  {
    const unsigned short* qbase =
        xb + ((size_t)(batch * S_LEN + q0 + r * 16 + l15)) * D_DIM + quad * 8;
    #pragma unroll
    for (int ks = 0; ks < 16; ++ks)
      qf[ks] = *(const bf16x8*)(qbase + ks * 32);
  }

  f32x4 O[2][8];
  #pragma unroll
  for (int m = 0; m < 2; ++m)
    #pragma unroll
    for (int n = 0; n < 8; ++n)
      O[m][n] = (f32x4){0.f, 0.f, 0.f, 0.f};

  const unsigned short* kbase =
      xb + ((size_t)(batch * S_LEN + c * 16 + l15)) * D_DIM + quad * 8;
  const unsigned short* vbase =
      xT + ((size_t)(batch * D_DIM + w * 128 + l15)) * S_LEN + quad * 8;

  for (int kt = 0; kt <= qtile; ++kt) {
    const int k0 = kt * 32;

    // ---- QK^T: S[16 rows r][16 keys c], contraction over D=512 ----
    f32x4 sacc = {0.f, 0.f, 0.f, 0.f};
    {
      const unsigned short* kp = kbase + (size_t)k0 * D_DIM;
      #pragma unroll
      for (int ks = 0; ks < 16; ++ks) {
        bf16x8 bfr = *(const bf16x8*)(kp + ks * 32);
        sacc = __builtin_amdgcn_mfma_f32_16x16x32_bf16(qf[ks], bfr, sacc, 0, 0, 0);
      }
    }
    // Causal mask only on the diagonal tile (k0 == q0).
    if (kt == qtile) {
      #pragma unroll
      for (int reg = 0; reg < 4; ++reg) {
        int row_l = r * 16 + quad * 4 + reg;
        int key_l = c * 16 + l15;
        if (key_l > row_l) sacc[reg] = -3e38f;
      }
    }

    // ---- online softmax: per-row max over this tile ----
    float pm[4];
    #pragma unroll
    for (int reg = 0; reg < 4; ++reg) pm[reg] = sacc[reg];
    #pragma unroll
    for (int off = 1; off < 16; off <<= 1) {
      #pragma unroll
      for (int reg = 0; reg < 4; ++reg)
        pm[reg] = fmaxf(pm[reg], __shfl_xor(pm[reg], off, 16));
    }
    if (l15 == 0) {
      #pragma unroll
      for (int reg = 0; reg < 4; ++reg)
        pmax[c][r * 16 + quad * 4 + reg] = pm[reg];
    }
    __syncthreads();  // barrier 1: pmax visible

    // All waves redundantly compute m_new / alpha for all 32 rows they touch.
    float alpha[2][4], mnr[2][4];
    #pragma unroll
    for (int mrow = 0; mrow < 2; ++mrow) {
      #pragma unroll
      for (int reg = 0; reg < 4; ++reg) {
        int row = mrow * 16 + quad * 4 + reg;
        float mt = fmaxf(pmax[0][row], pmax[1][row]);
        float mo = mbuf[row];
        float mn = fmaxf(mo, mt);
        mnr[mrow][reg] = mn;
        alpha[mrow][reg] = __expf(mo - mn);
      }
    }

    // P = exp(S - m_new); row-sum partials; stash P (bf16) for the PV matmul.
    float p[4], ps[4];
    #pragma unroll
    for (int reg = 0; reg < 4; ++reg) {
      p[reg] = __expf(sacc[reg] - mnr[r][reg]);
      ps[reg] = p[reg];
    }
    #pragma unroll
    for (int off = 1; off < 16; off <<= 1) {
      #pragma unroll
      for (int reg = 0; reg < 4; ++reg)
        ps[reg] += __shfl_xor(ps[reg], off, 16);
    }
    if (l15 == 0) {
      #pragma unroll
      for (int reg = 0; reg < 4; ++reg)
        psum[c][r * 16 + quad * 4 + reg] = ps[reg];
    }
    #pragma unroll
    for (int reg = 0; reg < 4; ++reg)
      Plds[(r * 16 + quad * 4 + reg) * 40 + c * 16 + l15] = f2b(p[reg]);
    __syncthreads();  // barrier 2: P + psum visible

    // ---- PV: O[32][128 slice] += P(32x32) * V(32x512 slice) ----
    bf16x8 pa[2];
    #pragma unroll
    for (int m = 0; m < 2; ++m)
      pa[m] = *(const bf16x8*)(&Plds[(m * 16 + l15) * 40 + quad * 8]);

    #pragma unroll
    for (int m = 0; m < 2; ++m)
      #pragma unroll
      for (int n = 0; n < 8; ++n)
        #pragma unroll
        for (int reg = 0; reg < 4; ++reg)
          O[m][n][reg] *= alpha[m][reg];

    #pragma unroll
    for (int n = 0; n < 8; ++n) {
      bf16x8 vb = *(const bf16x8*)(vbase + (size_t)n * 16 * S_LEN + k0);
      O[0][n] = __builtin_amdgcn_mfma_f32_16x16x32_bf16(pa[0], vb, O[0][n], 0, 0, 0);
      O[1][n] = __builtin_amdgcn_mfma_f32_16x16x32_bf16(pa[1], vb, O[1][n], 0, 0, 0);
    }

    // l / m state update (c==0 waves own rows r*16..r*16+15).
    if (c == 0 && l15 == 0) {
      #pragma unroll
      for (int reg = 0; reg < 4; ++reg) {
        int row = r * 16 + quad * 4 + reg;
        float ln = alpha[r][reg] * lbuf[row] + psum[0][row] + psum[1][row];
        lbuf[row] = ln;
        mbuf[row] = mnr[r][reg];
      }
    }
  }

  __syncthreads();
  float invl[2][4];
  #pragma unroll
  for (int m = 0; m < 2; ++m)
    #pragma unroll
    for (int reg = 0; reg < 4; ++reg)
      invl[m][reg] = 1.0f / lbuf[m * 16 + quad * 4 + reg];

  #pragma unroll
  for (int m = 0; m < 2; ++m)
    #pragma unroll
    for (int n = 0; n < 8; ++n)
      #pragma unroll
      for (int reg = 0; reg < 4; ++reg)
        out[((size_t)(batch * S_LEN + q0 + m * 16 + quad * 4 + reg)) * D_DIM +
            w * 128 + n * 16 + l15] = O[m][n][reg] * invl[m][reg];
}

extern "C" void kernel_launch(void* const* d_in, const int* in_sizes, int n_in,
                              void* d_out, int out_size, void* d_ws, size_t ws_size,
                              hipStream_t stream) {
  (void)in_sizes; (void)n_in; (void)out_size; (void)ws_size;
  const float* x = (const float*)d_in[0];
  float* out = (float*)d_out;
  unsigned short* xb = (unsigned short*)d_ws;                         // 16 MiB
  unsigned short* xT = (unsigned short*)((char*)d_ws + (16u << 20));  // 16 MiB
  // needs ws_size >= 32 MiB (8*2048*512*2 bytes per copy)
  convert_transpose_kernel<<<2048, 256, 0, stream>>>(x, xb, xT);
  attn_kernel<<<512, 256, 0, stream>>>(xb, xT, out);
}

// Round 2
// 345.132 us; speedup vs baseline: 1.1516x; 1.1516x over previous
//
#include <hip/hip_runtime.h>

// CausalSelfAttention: B=8, S=2048, D=512, fp32 in/out, Q=K=V=x, no scale.
// Round 2: wave-autonomous flash attention.
//  - Each wave owns 16 Q-rows: softmax m/l in registers, row reductions via DPP
//    (quad_perm + row_ror within 16-lane rows), P transform via wave-private LDS.
//    ZERO __syncthreads in the K-loop -> loads pipeline across iterations.
//  - K-tile = 64 keys/iter: 64 QK MFMA (4 independent acc chains) + 64 PV MFMA.
//  - Load balance: pair 16-row stripe p with 127-p; split the pair's ~2064 keys
//    between 2 waves (A: stripe p fully + head of stripe 127-p; B: tail of
//    127-p). Every wave processes 1008..1056 keys. One barrier + LDS merge for
//    the split heavy stripe.
//  - 256 blocks x 4 waves = 1024 uniform waves (1 wave/SIMD, big register tile).
// ws layout: [0,16MiB) x_bf16 [B][S][D]; [16MiB,32MiB) xT_bf16 [B][D][S].

#define S_LEN 2048
#define D_DIM 512

typedef short bf16x8 __attribute__((ext_vector_type(8)));
typedef float f32x4 __attribute__((ext_vector_type(4)));

__device__ __forceinline__ unsigned short f2b_rne(float f) {
  unsigned int u = __float_as_uint(f);
  unsigned int r = (u + 0x7FFFu + ((u >> 16) & 1u)) >> 16;
  return (unsigned short)r;
}
__device__ __forceinline__ unsigned short f2b_fast(float f) {
  return (unsigned short)((__float_as_uint(f) + 0x8000u) >> 16);
}

// DPP cross-lane (within 16-lane rows; our MFMA C-layout rows are lanes
// quad*16..quad*16+15, so "row" DPP ops hit exactly one reduction group).
template <int CTRL>
__device__ __forceinline__ float dppf(float x) {
  return __uint_as_float((unsigned)__builtin_amdgcn_update_dpp(
      0, (int)__float_as_uint(x), CTRL, 0xF, 0xF, true));
}
__device__ __forceinline__ float red16_max(float v) {
  v = fmaxf(v, dppf<0xB1>(v));    // quad_perm [1,0,3,2]  (xor 1)
  v = fmaxf(v, dppf<0x4E>(v));    // quad_perm [2,3,0,1]  (xor 2)
  v = fmaxf(v, dppf<0x124>(v));   // row_ror:4
  v = fmaxf(v, dppf<0x128>(v));   // row_ror:8
  return v;
}
__device__ __forceinline__ float red16_sum(float v) {
  v += dppf<0xB1>(v);
  v += dppf<0x4E>(v);
  v += dppf<0x124>(v);
  v += dppf<0x128>(v);
  return v;
}

// ---------------------------------------------------------------------------
// Pre-pass: fp32 -> bf16 row-major + transposed copy. 64x64 tiles via LDS.
// XOR-swizzled LDS layout: elem(d,s) = d*72 + (s ^ (((d>>3)&3)<<3)).
// Write conflicts drop 16-way -> 2-way; reads stay ~4-way on 2-dword vectors.
// ---------------------------------------------------------------------------
__global__ void convert_transpose_kernel(const float* __restrict__ x,
                                         unsigned short* __restrict__ xb,
                                         unsigned short* __restrict__ xT) {
  __shared__ unsigned short lds[64 * 72];
  const int bid = blockIdx.x;
  const int b   = bid >> 8;
  const int rem = bid & 255;
  const int s0  = (rem >> 3) * 64;
  const int d0  = (rem & 7) * 64;
  const int tid = threadIdx.x;
  #pragma unroll
  for (int it = 0; it < 4; ++it) {
    int idx = it * 256 + tid;
    int row = idx >> 4;              // s_local 0..63
    int c4  = (idx & 15) * 4;        // d_local 0..60
    const float4 v = *(const float4*)(x + ((size_t)(b * S_LEN + s0 + row)) * D_DIM + d0 + c4);
    unsigned short h[4] = {f2b_rne(v.x), f2b_rne(v.y), f2b_rne(v.z), f2b_rne(v.w)};
    ushort4 o; o.x = h[0]; o.y = h[1]; o.z = h[2]; o.w = h[3];
    *(ushort4*)(xb + ((size_t)(b * S_LEN + s0 + row)) * D_DIM + d0 + c4) = o;
    #pragma unroll
    for (int ii = 0; ii < 4; ++ii) {
      int dd = c4 + ii;
      int sw = ((dd >> 3) & 3) << 3;
      lds[dd * 72 + (row ^ sw)] = h[ii];
    }
  }
  __syncthreads();
  #pragma unroll
  for (int it = 0; it < 4; ++it) {
    int idx  = it * 256 + tid;
    int drow = idx >> 4;             // d_local 0..63
    int s4   = (idx & 15) * 4;       // s_local 0..60
    int sw   = ((drow >> 3) & 3) << 3;
    ushort4 o = *(ushort4*)(&lds[drow * 72 + (s4 ^ sw)]);
    *(ushort4*)(xT + ((size_t)(b * D_DIM + d0 + drow)) * S_LEN + s0 + s4) = o;
  }
}

// ---------------------------------------------------------------------------
// Wave-autonomous flash over key-tiles [kt0, kt1) for 16 rows at rowbase.
// MFMA 16x16x32 layouts: A[m=l15][k=quad*8+j], B[k=quad*8+j][n=l15],
// C/D: col=l15, row=quad*4+reg.
// ---------------------------------------------------------------------------
__device__ __forceinline__ void flash_range(
    const unsigned short* __restrict__ xb,
    const unsigned short* __restrict__ xT,
    int batch, int rowbase, int kt0, int kt1, bool maskLast,
    unsigned short* __restrict__ Pw, int l15, int quad,
    f32x4 (&O)[32], float (&m)[4], float (&l)[4]) {
  if (kt0 >= kt1) return;

  bf16x8 qf[16];
  {
    const unsigned short* qbase =
        xb + ((size_t)(batch * S_LEN + rowbase + l15)) * D_DIM + quad * 8;
    #pragma unroll
    for (int ks = 0; ks < 16; ++ks) qf[ks] = *(const bf16x8*)(qbase + ks * 32);
  }
  const unsigned short* kroot =
      xb + ((size_t)batch * S_LEN + l15) * D_DIM + quad * 8;
  const unsigned short* vroot =
      xT + ((size_t)(batch * D_DIM + l15)) * S_LEN + quad * 8;

  for (int kt = kt0; kt < kt1; ++kt) {
    const int k0 = kt * 64;

    // ---- QK^T: S[16 rows][64 keys], 4 independent accumulator chains ----
    f32x4 sacc[4];
    #pragma unroll
    for (int cg = 0; cg < 4; ++cg) sacc[cg] = (f32x4){0.f, 0.f, 0.f, 0.f};
    const unsigned short* kp = kroot + (size_t)k0 * D_DIM;
    #pragma unroll
    for (int ks = 0; ks < 16; ++ks) {
      #pragma unroll
      for (int cg = 0; cg < 4; ++cg) {
        bf16x8 kf = *(const bf16x8*)(kp + (size_t)cg * 16 * D_DIM + ks * 32);
        sacc[cg] = __builtin_amdgcn_mfma_f32_16x16x32_bf16(qf[ks], kf, sacc[cg], 0, 0, 0);
      }
    }
    if (maskLast && kt == kt1 - 1) {
      #pragma unroll
      for (int cg = 0; cg < 4; ++cg)
        #pragma unroll
        for (int r = 0; r < 4; ++r) {
          int key = k0 + cg * 16 + l15;
          int row = rowbase + quad * 4 + r;
          if (key > row) sacc[cg][r] = -3e38f;  // exp -> exact 0, P-col zero
        }
    }

    // ---- online softmax (all in registers; DPP row reductions) ----
    float mt[4], alpha[4];
    #pragma unroll
    for (int r = 0; r < 4; ++r) {
      float v = fmaxf(fmaxf(sacc[0][r], sacc[1][r]), fmaxf(sacc[2][r], sacc[3][r]));
      mt[r] = red16_max(v);
    }
    bool needAny = (mt[0] > m[0]) | (mt[1] > m[1]) | (mt[2] > m[2]) | (mt[3] > m[3]);
    unsigned long long bal = __ballot(needAny);
    if (bal) {
      #pragma unroll
      for (int r = 0; r < 4; ++r) {
        float mn = fmaxf(m[r], mt[r]);
        alpha[r] = __expf(m[r] - mn);
        m[r] = mn;
      }
    } else {
      #pragma unroll
      for (int r = 0; r < 4; ++r) alpha[r] = 1.0f;
    }
    float p[4][4];
    #pragma unroll
    for (int cg = 0; cg < 4; ++cg)
      #pragma unroll
      for (int r = 0; r < 4; ++r) p[cg][r] = __expf(sacc[cg][r] - m[r]);
    #pragma unroll
    for (int r = 0; r < 4; ++r) {
      float s = (p[0][r] + p[1][r]) + (p[2][r] + p[3][r]);
      float rs = red16_sum(s);
      l[r] = l[r] * alpha[r] + rs;
    }

    // ---- P: C-layout -> A-layout via wave-private LDS (lgkmcnt only) ----
    #pragma unroll
    for (int cg = 0; cg < 4; ++cg)
      #pragma unroll
      for (int r = 0; r < 4; ++r)
        Pw[(quad * 4 + r) * 72 + cg * 16 + l15] = f2b_fast(p[cg][r]);
    bf16x8 pa0 = *(const bf16x8*)(Pw + l15 * 72 + quad * 8);
    bf16x8 pa1 = *(const bf16x8*)(Pw + l15 * 72 + 32 + quad * 8);

    if (bal) {
      #pragma unroll
      for (int n = 0; n < 32; ++n)
        #pragma unroll
        for (int r = 0; r < 4; ++r) O[n][r] *= alpha[r];
    }

    // ---- PV: O[16 rows][512] += P(16x64) * V(64x512) ----
    const unsigned short* vp = vroot + k0;
    #pragma unroll
    for (int n = 0; n < 32; ++n) {
      bf16x8 v0 = *(const bf16x8*)(vp + (size_t)n * 16 * S_LEN);
      bf16x8 v1 = *(const bf16x8*)(vp + (size_t)n * 16 * S_LEN + 32);
      O[n] = __builtin_amdgcn_mfma_f32_16x16x32_bf16(pa0, v0, O[n], 0, 0, 0);
      O[n] = __builtin_amdgcn_mfma_f32_16x16x32_bf16(pa1, v1, O[n], 0, 0, 0);
    }
  }
}

// ---------------------------------------------------------------------------
// 256 blocks x 4 waves. Block bid: batch = bid&7 (XCD-pinned), bi = bid>>3.
// Waves (j = w>>1, isB = w&1) handle pair p = bi*2+j:
//   light stripe L = p (rows 16p, keys kL = 16p+16),
//   heavy stripe H = 127-p (rows 2032-16p, keys kH = 2048-16p).
//   split x ~ (kH-kL)/2 rounded to 64:
//     waveA: H keys [0,x) (unmasked; x <= rows of H), then L fully, writes L.
//     waveB: H keys [x,kH) (masked tail), then merges with A's partial via LDS.
// Every wave: ~16 key-tile iterations (uniform to +-1 tile).
// ---------------------------------------------------------------------------
__global__ __launch_bounds__(256, 1)
void attn_kernel(const unsigned short* __restrict__ xb,
                 const unsigned short* __restrict__ xT,
                 float* __restrict__ out) {
  __shared__ float Om[2][16 * 516];          // heavy-stripe partial O (pad 516)
  __shared__ float mS[2][16], lS[2][16];
  __shared__ unsigned short Plds[4][16 * 72];

  const int bid = blockIdx.x;
  const int batch = bid & 7;
  const int bi = bid >> 3;                   // 0..31
  const int tid = threadIdx.x;
  const int w = tid >> 6;
  const int lane = tid & 63;
  const int l15 = lane & 15, quad = lane >> 4;
  const int j = w >> 1;
  const int isB = w & 1;
  const int p = bi * 2 + j;                  // 0..63
  const int kL = 16 * p + 16;
  const int kH = S_LEN - 16 * p;
  const int rL = 16 * p;
  const int rH = S_LEN - 16 * p - 16;
  int x = ((1016 - 16 * p) + 32) & ~63;
  if (x < 0) x = 0;
  unsigned short* Pw = Plds[w];

  f32x4 O[32];
  float m[4], l[4];
  #pragma unroll
  for (int n = 0; n < 32; ++n) O[n] = (f32x4){0.f, 0.f, 0.f, 0.f};
  #pragma unroll
  for (int r = 0; r < 4; ++r) { m[r] = -3e38f; l[r] = 0.f; }

  if (!isB) {
    // ---- wave A: head of heavy stripe (no masking), dump partials ----
    flash_range(xb, xT, batch, rH, 0, x >> 6, false, Pw, l15, quad, O, m, l);
    #pragma unroll
    for (int n = 0; n < 32; ++n)
      #pragma unroll
      for (int r = 0; r < 4; ++r)
        Om[j][(quad * 4 + r) * 516 + n * 16 + l15] = O[n][r];
    if (l15 == 0) {
      #pragma unroll
      for (int r = 0; r < 4; ++r) {
        mS[j][quad * 4 + r] = m[r];
        lS[j][quad * 4 + r] = l[r];
      }
    }
    // ---- wave A: light stripe, full, write out ----
    #pragma unroll
    for (int n = 0; n < 32; ++n) O[n] = (f32x4){0.f, 0.f, 0.f, 0.f};
    #pragma unroll
    for (int r = 0; r < 4; ++r) { m[r] = -3e38f; l[r] = 0.f; }
    flash_range(xb, xT, batch, rL, 0, (kL + 63) >> 6, true, Pw, l15, quad, O, m, l);
    float invl[4];
    #pragma unroll
    for (int r = 0; r < 4; ++r) invl[r] = 1.f / l[r];
    float* ob = out + ((size_t)(batch * S_LEN + rL)) * D_DIM;
    #pragma unroll
    for (int n = 0; n < 32; ++n)
      #pragma unroll
      for (int r = 0; r < 4; ++r)
        ob[(size_t)(quad * 4 + r) * D_DIM + n * 16 + l15] = O[n][r] * invl[r];
  } else {
    // ---- wave B: tail of heavy stripe (masked diagonal) ----
    flash_range(xb, xT, batch, rH, x >> 6, (kH + 63) >> 6, true, Pw, l15, quad, O, m, l);
  }

  __syncthreads();

  if (isB) {
    float aA[4], aB[4], invl[4];
    #pragma unroll
    for (int r = 0; r < 4; ++r) {
      float mA = mS[j][quad * 4 + r], lA = lS[j][quad * 4 + r];
      float mm = fmaxf(mA, m[r]);
      aA[r] = __expf(mA - mm);
      aB[r] = __expf(m[r] - mm);
      invl[r] = 1.f / (lA * aA[r] + l[r] * aB[r]);
    }
    float* ob = out + ((size_t)(batch * S_LEN + rH)) * D_DIM;
    #pragma unroll
    for (int n = 0; n < 32; ++n)
      #pragma unroll
      for (int r = 0; r < 4; ++r) {
        float oa = Om[j][(quad * 4 + r) * 516 + n * 16 + l15];
        ob[(size_t)(quad * 4 + r) * D_DIM + n * 16 + l15] =
            (oa * aA[r] + O[n][r] * aB[r]) * invl[r];
      }
  }
}

extern "C" void kernel_launch(void* const* d_in, const int* in_sizes, int n_in,
                              void* d_out, int out_size, void* d_ws, size_t ws_size,
                              hipStream_t stream) {
  (void)in_sizes; (void)n_in; (void)out_size; (void)ws_size;
  const float* x = (const float*)d_in[0];
  float* out = (float*)d_out;
  unsigned short* xb = (unsigned short*)d_ws;                         // 16 MiB
  unsigned short* xT = (unsigned short*)((char*)d_ws + (16u << 20));  // 16 MiB
  convert_transpose_kernel<<<2048, 256, 0, stream>>>(x, xb, xT);
  attn_kernel<<<256, 256, 0, stream>>>(xb, xT, out);
}

// Round 3
// 233.971 us; speedup vs baseline: 1.6987x; 1.4751x over previous
//
#include <hip/hip_runtime.h>

// CausalSelfAttention: B=8, S=2048, D=512, fp32 in/out, Q=K=V=x, no scale.
// Round 3: fragment-packed operands + LDS tile staging.
//   Prepass packs x (bf16) into MFMA-fragment order:
//     Kf[b][kg:128][db:16][lane:64][8]  elem = x[b][16*kg+l15][32*db+8*quad+j]
//       (serves both Q A-frags and K B-frags; frag-block = 1KB contiguous)
//     Vf[b][dg:32][kb:64][lane:64][8]   elem = x[b][32*kb+8*quad+j][16*dg+l15]
//       (serves V B-frags for PV)
//   Attention: 512 blocks x 128 thr (2 waves). Block = 32 Q-rows (wave w owns
//   16 rows, full D, register softmax as round 2). Per 32-key tile: stage
//   K(32KB)+V(32KB) into LDS via global_load_lds width=16 (frag order matches
//   the wave-uniform-base + lane*16 semantics), then ds_read_b128 fragments.
//   Heavy-first launch: bid<256 -> t=63..32, bid>=256 -> t=0..31 so co-resident
//   block pairs (bid, bid+256) sum to ~constant work.
// ws: [0,16MiB) Kf, [16MiB,32MiB) Vf.

#define S_LEN 2048
#define D_DIM 512
#define BATCH_ELEMS 1048576  // 2 MiB bf16 per batch per array

typedef short s16x8 __attribute__((ext_vector_type(8)));
typedef float f32x4 __attribute__((ext_vector_type(4)));

__device__ __forceinline__ unsigned short f2b_rne(float f) {
  unsigned int u = __float_as_uint(f);
  return (unsigned short)((u + 0x7FFFu + ((u >> 16) & 1u)) >> 16);
}
__device__ __forceinline__ unsigned short f2b_fast(float f) {
  return (unsigned short)((__float_as_uint(f) + 0x8000u) >> 16);
}

template <int CTRL>
__device__ __forceinline__ float dppf(float x) {
  return __uint_as_float((unsigned)__builtin_amdgcn_update_dpp(
      0, (int)__float_as_uint(x), CTRL, 0xF, 0xF, true));
}
__device__ __forceinline__ float red16_max(float v) {
  v = fmaxf(v, dppf<0xB1>(v));   // xor 1
  v = fmaxf(v, dppf<0x4E>(v));   // xor 2
  v = fmaxf(v, dppf<0x124>(v));  // row_ror:4
  v = fmaxf(v, dppf<0x128>(v));  // row_ror:8
  return v;
}
__device__ __forceinline__ float red16_sum(float v) {
  v += dppf<0xB1>(v);
  v += dppf<0x4E>(v);
  v += dppf<0x124>(v);
  v += dppf<0x128>(v);
  return v;
}

// ---------------------------------------------------------------------------
// Prepass: pack x into Kf and Vf fragment order. 2048 blocks x 256 thr,
// 64x64 tile per block. A = [s][d] bf16, T = [d][s] bf16 (stride 72, 16B-al).
// ---------------------------------------------------------------------------
__global__ void pack_kernel(const float* __restrict__ x,
                            unsigned short* __restrict__ Kf,
                            unsigned short* __restrict__ Vf) {
  __shared__ unsigned short A[64 * 72];
  __shared__ unsigned short T[64 * 72];
  const int bid = blockIdx.x;
  const int b = bid >> 8, rem = bid & 255;
  const int s0 = (rem >> 3) * 64, d0 = (rem & 7) * 64;
  const int tid = threadIdx.x;

  // pass 1: load + convert, fill A[s][d]
  #pragma unroll
  for (int it = 0; it < 2; ++it) {
    int slot = it * 256 + tid;          // 0..511
    int row = slot >> 3, c = slot & 7;  // row 0..63, 8-col group
    const float* src = x + ((size_t)(b * S_LEN + s0 + row)) * D_DIM + d0 + c * 8;
    const float4 v0 = *(const float4*)(src);
    const float4 v1 = *(const float4*)(src + 4);
    s16x8 o;
    o[0] = (short)f2b_rne(v0.x); o[1] = (short)f2b_rne(v0.y);
    o[2] = (short)f2b_rne(v0.z); o[3] = (short)f2b_rne(v0.w);
    o[4] = (short)f2b_rne(v1.x); o[5] = (short)f2b_rne(v1.y);
    o[6] = (short)f2b_rne(v1.z); o[7] = (short)f2b_rne(v1.w);
    *(s16x8*)&A[row * 72 + c * 8] = o;
  }
  __syncthreads();

  // pass 2: transpose A -> T in 4x4 micro-blocks (vector b64 ops)
  {
    int sr = tid >> 4, sc = tid & 15;
    ushort4 a0 = *(const ushort4*)&A[(4 * sr + 0) * 72 + 4 * sc];
    ushort4 a1 = *(const ushort4*)&A[(4 * sr + 1) * 72 + 4 * sc];
    ushort4 a2 = *(const ushort4*)&A[(4 * sr + 2) * 72 + 4 * sc];
    ushort4 a3 = *(const ushort4*)&A[(4 * sr + 3) * 72 + 4 * sc];
    ushort4 t0; t0.x = a0.x; t0.y = a1.x; t0.z = a2.x; t0.w = a3.x;
    ushort4 t1; t1.x = a0.y; t1.y = a1.y; t1.z = a2.y; t1.w = a3.y;
    ushort4 t2; t2.x = a0.z; t2.y = a1.z; t2.z = a2.z; t2.w = a3.z;
    ushort4 t3; t3.x = a0.w; t3.y = a1.w; t3.z = a2.w; t3.w = a3.w;
    *(ushort4*)&T[(4 * sc + 0) * 72 + 4 * sr] = t0;
    *(ushort4*)&T[(4 * sc + 1) * 72 + 4 * sr] = t1;
    *(ushort4*)&T[(4 * sc + 2) * 72 + 4 * sr] = t2;
    *(ushort4*)&T[(4 * sc + 3) * 72 + 4 * sr] = t3;
  }
  __syncthreads();

  // pass 3: emit fragment blocks (each 64 consecutive threads write 1KB)
  #pragma unroll
  for (int it = 0; it < 2; ++it) {
    int slot = it * 256 + tid;
    int frag = slot >> 6;               // 0..7
    int lane = slot & 63;
    int l15 = lane & 15, quad = lane >> 4;
    int f1 = frag >> 1, f0 = frag & 1;  // f1: 0..3, f0: 0..1
    // Kf: kgl=f1 (16 rows), dbl=f0 (32 cols)
    {
      s16x8 val = *(const s16x8*)&A[(f1 * 16 + l15) * 72 + f0 * 32 + quad * 8];
      size_t kg = (size_t)(s0 >> 4) + f1, db = (size_t)(d0 >> 5) + f0;
      *(s16x8*)(Kf + (size_t)b * BATCH_ELEMS + (kg * 16 + db) * 512 + lane * 8) = val;
    }
    // Vf: dgl=f1 (16 cols), kbl=f0 (32 rows)
    {
      s16x8 val = *(const s16x8*)&T[(f1 * 16 + l15) * 72 + f0 * 32 + quad * 8];
      size_t dg = (size_t)(d0 >> 4) + f1, kb = (size_t)(s0 >> 5) + f0;
      *(s16x8*)(Vf + (size_t)b * BATCH_ELEMS + (dg * 64 + kb) * 512 + lane * 8) = val;
    }
  }
}

// ---------------------------------------------------------------------------
// Flash attention, LDS-staged tiles.
// MFMA 16x16x32 layouts: A[m=l15][k=quad*8+j], B[k=quad*8+j][n=l15],
// C/D: col=l15, row=quad*4+reg.
// ---------------------------------------------------------------------------
__global__ __launch_bounds__(128, 2)
void attn_kernel(const unsigned short* __restrict__ Kf,
                 const unsigned short* __restrict__ Vf,
                 float* __restrict__ out) {
  __shared__ unsigned short ldsK[16384];   // 32 frag-blocks (kg2*16+db)*512+lane*8
  __shared__ unsigned short ldsV[16384];   // 32 frag-blocks dg*512+lane*8
  __shared__ unsigned short Pw[2][16 * 40];

  const int bid = blockIdx.x;
  const int bat = bid & 7;
  const int t = (bid < 256) ? (63 - (bid >> 3)) : ((bid - 256) >> 3);
  const int q0 = t * 32;
  const int tid = threadIdx.x;
  const int w = tid >> 6;
  const int lane = tid & 63;
  const int l15 = lane & 15, quad = lane >> 4;
  const size_t batOff = (size_t)bat * BATCH_ELEMS;

  // Q fragments (from Kf layout): wave w owns rows q0+16w .. +15, full D.
  s16x8 qf[16];
  {
    const unsigned short* qb = Kf + batOff + ((size_t)(2 * t + w) * 16) * 512 + lane * 8;
    #pragma unroll
    for (int db = 0; db < 16; ++db) qf[db] = *(const s16x8*)(qb + db * 512);
  }

  f32x4 O[32];
  float m[4], l[4];
  #pragma unroll
  for (int n = 0; n < 32; ++n) O[n] = (f32x4){0.f, 0.f, 0.f, 0.f};
  #pragma unroll
  for (int r = 0; r < 4; ++r) { m[r] = -3e38f; l[r] = 0.f; }

  for (int kt = 0; kt <= t; ++kt) {
    __syncthreads();  // previous tile's LDS reads complete before overwrite
    // ---- stage K tile (32KB) + V tile (32KB), split between the 2 waves ----
    {
      const unsigned short* ks =
          Kf + batOff + (size_t)kt * 16384 + (size_t)(w * 16) * 512 + lane * 8;
      #pragma unroll
      for (int i = 0; i < 16; ++i) {
        __builtin_amdgcn_global_load_lds(
            (const __attribute__((address_space(1))) unsigned int*)(ks + i * 512),
            (__attribute__((address_space(3))) unsigned int*)&ldsK[(w * 16 + i) * 512],
            16, 0, 0);
      }
      const unsigned short* vs = Vf + batOff + (size_t)kt * 512 + lane * 8;
      #pragma unroll
      for (int i = 0; i < 16; ++i) {
        int dg = w * 16 + i;
        __builtin_amdgcn_global_load_lds(
            (const __attribute__((address_space(1))) unsigned int*)(vs + (size_t)dg * 32768),
            (__attribute__((address_space(3))) unsigned int*)&ldsV[dg * 512],
            16, 0, 0);
      }
    }
    __syncthreads();  // staging visible to both waves

    // ---- QK^T: S[16 rows][32 keys] ----
    f32x4 sacc[2];
    sacc[0] = (f32x4){0.f, 0.f, 0.f, 0.f};
    sacc[1] = (f32x4){0.f, 0.f, 0.f, 0.f};
    #pragma unroll
    for (int db = 0; db < 16; ++db) {
      s16x8 k0 = *(const s16x8*)&ldsK[(db)*512 + lane * 8];
      s16x8 k1 = *(const s16x8*)&ldsK[(16 + db) * 512 + lane * 8];
      sacc[0] = __builtin_amdgcn_mfma_f32_16x16x32_bf16(qf[db], k0, sacc[0], 0, 0, 0);
      sacc[1] = __builtin_amdgcn_mfma_f32_16x16x32_bf16(qf[db], k1, sacc[1], 0, 0, 0);
    }
    if (kt == t) {  // causal mask on diagonal tile
      #pragma unroll
      for (int kg2 = 0; kg2 < 2; ++kg2)
        #pragma unroll
        for (int r = 0; r < 4; ++r) {
          int key = kt * 32 + kg2 * 16 + l15;
          int row = q0 + 16 * w + quad * 4 + r;
          if (key > row) sacc[kg2][r] = -3e38f;
        }
    }

    // ---- online softmax (registers + DPP) ----
    float mt[4], alpha[4];
    #pragma unroll
    for (int r = 0; r < 4; ++r)
      mt[r] = red16_max(fmaxf(sacc[0][r], sacc[1][r]));
    bool needAny = (mt[0] > m[0]) | (mt[1] > m[1]) | (mt[2] > m[2]) | (mt[3] > m[3]);
    unsigned long long bal = __ballot(needAny);
    if (bal) {
      #pragma unroll
      for (int r = 0; r < 4; ++r) {
        float mn = fmaxf(m[r], mt[r]);
        alpha[r] = __expf(m[r] - mn);
        m[r] = mn;
      }
    } else {
      #pragma unroll
      for (int r = 0; r < 4; ++r) alpha[r] = 1.0f;
    }
    float p[2][4];
    #pragma unroll
    for (int kg2 = 0; kg2 < 2; ++kg2)
      #pragma unroll
      for (int r = 0; r < 4; ++r) p[kg2][r] = __expf(sacc[kg2][r] - m[r]);
    #pragma unroll
    for (int r = 0; r < 4; ++r)
      l[r] = l[r] * alpha[r] + red16_sum(p[0][r] + p[1][r]);

    // ---- P: C-layout -> A-layout via wave-private LDS ----
    #pragma unroll
    for (int kg2 = 0; kg2 < 2; ++kg2)
      #pragma unroll
      for (int r = 0; r < 4; ++r)
        Pw[w][(quad * 4 + r) * 40 + kg2 * 16 + l15] = f2b_fast(p[kg2][r]);
    s16x8 pa = *(const s16x8*)&Pw[w][l15 * 40 + quad * 8];

    if (bal) {
      #pragma unroll
      for (int n = 0; n < 32; ++n)
        #pragma unroll
        for (int r = 0; r < 4; ++r) O[n][r] *= alpha[r];
    }

    // ---- PV: O[16 rows][512] += P(16x32) * V(32x512) ----
    #pragma unroll
    for (int dg = 0; dg < 32; ++dg) {
      s16x8 vf = *(const s16x8*)&ldsV[dg * 512 + lane * 8];
      O[dg] = __builtin_amdgcn_mfma_f32_16x16x32_bf16(pa, vf, O[dg], 0, 0, 0);
    }
  }

  // ---- epilogue ----
  float invl[4];
  #pragma unroll
  for (int r = 0; r < 4; ++r) invl[r] = 1.0f / l[r];
  float* ob = out + ((size_t)(bat * S_LEN + q0 + 16 * w)) * D_DIM;
  #pragma unroll
  for (int dg = 0; dg < 32; ++dg)
    #pragma unroll
    for (int r = 0; r < 4; ++r)
      ob[(size_t)(quad * 4 + r) * D_DIM + dg * 16 + l15] = O[dg][r] * invl[r];
}

extern "C" void kernel_launch(void* const* d_in, const int* in_sizes, int n_in,
                              void* d_out, int out_size, void* d_ws, size_t ws_size,
                              hipStream_t stream) {
  (void)in_sizes; (void)n_in; (void)out_size; (void)ws_size;
  const float* x = (const float*)d_in[0];
  float* out = (float*)d_out;
  unsigned short* Kf = (unsigned short*)d_ws;                         // 16 MiB
  unsigned short* Vf = (unsigned short*)((char*)d_ws + (16u << 20));  // 16 MiB
  pack_kernel<<<2048, 256, 0, stream>>>(x, Kf, Vf);
  attn_kernel<<<512, 128, 0, stream>>>(Kf, Vf, out);
}